// Round 2
// baseline (2918.903 us; speedup 1.0000x reference)
//
#include <hip/hip_runtime.h>

#define N_NODES 100000
#define E_EDGES 1600000
#define D 128

// ---------- threefry2x32, key=(0,42), ctr=(0,i) ----------
// JAX partitionable path for 32-bit width returns XOR of both output words:
//   bits1, bits2 = threefry2x32(k, ctr_hi, ctr_lo);  bits = bits1 ^ bits2
__device__ __forceinline__ unsigned int rotl32(unsigned int x, int r) {
  return (x << r) | (x >> (32 - r));
}

__device__ __forceinline__ unsigned int threefry_bits(unsigned int ctr) {
  const unsigned int ks0 = 0u, ks1 = 42u;
  const unsigned int ks2 = ks0 ^ ks1 ^ 0x1BD11BDAu;
  unsigned int x0 = ks0;        // ctr_hi (0) + ks0
  unsigned int x1 = ctr + ks1;  // ctr_lo + ks1
#define TF_ROUND(R) { x0 += x1; x1 = rotl32(x1, R); x1 ^= x0; }
  TF_ROUND(13) TF_ROUND(15) TF_ROUND(26) TF_ROUND(6)
  x0 += ks1; x1 += ks2 + 1u;
  TF_ROUND(17) TF_ROUND(29) TF_ROUND(16) TF_ROUND(24)
  x0 += ks2; x1 += ks0 + 2u;
  TF_ROUND(13) TF_ROUND(15) TF_ROUND(26) TF_ROUND(6)
  x0 += ks0; x1 += ks1 + 3u;
  TF_ROUND(17) TF_ROUND(29) TF_ROUND(16) TF_ROUND(24)
  x0 += ks1; x1 += ks2 + 4u;
  TF_ROUND(13) TF_ROUND(15) TF_ROUND(26) TF_ROUND(6)
  x0 += ks2; x1 += ks0 + 5u;
#undef TF_ROUND
  return x0 ^ x1;   // <-- the fix: XOR both halves (partitionable 32-bit path)
}

// ---------- degree count over dst ----------
__global__ __launch_bounds__(256) void k_deg(const int* __restrict__ dst,
                                             int* __restrict__ deg) {
  int e = blockIdx.x * 256 + threadIdx.x;
  if (e < E_EDGES) atomicAdd(&deg[dst[e]], 1);
}

// ---------- dinv = rsqrt(deg + 1)  (self loop), stored in place as float bits ----------
__global__ __launch_bounds__(256) void k_dinv(int* __restrict__ deg) {
  int i = blockIdx.x * 256 + threadIdx.x;
  if (i < N_NODES) {
    float v = rsqrtf((float)(deg[i] + 1));
    deg[i] = __float_as_int(v);
  }
}

// ---------- h = x @ W ; tile 32 rows x 128 cols, K split in 2 halves ----------
__global__ __launch_bounds__(256) void k_gemm(const float* __restrict__ x,
                                              const float* __restrict__ w,
                                              float* __restrict__ h) {
  __shared__ float Ws[64 * 128];   // 32 KB
  __shared__ float Xs[32 * 68];    // padded stride 68 (16B-aligned, bank-shifted)
  const int t  = threadIdx.x;
  const int tx = t & 31;   // col group: cols 4*tx..4*tx+3
  const int ty = t >> 5;   // row group: rows 4*ty..4*ty+3 (0..7)
  const int row0 = blockIdx.x * 32;
  float4 acc[4];
  acc[0] = acc[1] = acc[2] = acc[3] = make_float4(0.f, 0.f, 0.f, 0.f);

  for (int kt = 0; kt < 2; ++kt) {
    const float4* wsrc = (const float4*)(w + kt * 64 * 128);
    float4* wdst = (float4*)Ws;
#pragma unroll
    for (int i = 0; i < 8; ++i) wdst[t + i * 256] = wsrc[t + i * 256];
#pragma unroll
    for (int i = 0; i < 2; ++i) {
      int idx = t + i * 256;          // 0..511
      int r   = idx >> 4;             // 0..31
      int c4  = idx & 15;             // 0..15
      float4 v = *(const float4*)(x + (long long)(row0 + r) * D + kt * 64 + c4 * 4);
      *(float4*)(&Xs[r * 68 + c4 * 4]) = v;
    }
    __syncthreads();
#pragma unroll 8
    for (int k = 0; k < 64; ++k) {
      float4 wv = *(const float4*)(&Ws[k * 128 + tx * 4]);
#pragma unroll
      for (int i = 0; i < 4; ++i) {
        float xv = Xs[(ty * 4 + i) * 68 + k];
        acc[i].x += xv * wv.x; acc[i].y += xv * wv.y;
        acc[i].z += xv * wv.z; acc[i].w += xv * wv.w;
      }
    }
    __syncthreads();
  }
#pragma unroll
  for (int i = 0; i < 4; ++i) {
    int r = row0 + ty * 4 + i;
    *(float4*)(h + (long long)r * D + tx * 4) = acc[i];
  }
}

// ---------- edge scatter: out[dst] += h[src] * dinv[src]*dinv[dst] ----------
__global__ __launch_bounds__(256) void k_scatter(const int* __restrict__ ei,
                                                 const float* __restrict__ h,
                                                 const float* __restrict__ dinv,
                                                 float* __restrict__ out) {
  int tid = blockIdx.x * 256 + threadIdx.x;  // < 51.2M, fits int
  int e = tid >> 5;
  int c = tid & 31;
  int s = ei[e];
  int d = ei[E_EDGES + e];
  float nrm = dinv[s] * dinv[d];
  float4 m = *(const float4*)(h + (long long)s * D + c * 4);
  float* o = out + (long long)d * D + c * 4;
  atomicAdd(o + 0, m.x * nrm);
  atomicAdd(o + 1, m.y * nrm);
  atomicAdd(o + 2, m.z * nrm);
  atomicAdd(o + 3, m.w * nrm);
}

// ---------- epilogue: self-loop + bias, ReLU, dropout (threefry), in place ----------
__global__ __launch_bounds__(256) void k_final(float* __restrict__ out,
                                               const float* __restrict__ h,
                                               const float* __restrict__ dinv,
                                               const float* __restrict__ bias) {
  int tid = blockIdx.x * 256 + threadIdx.x;  // < 3.2M
  int i = tid * 4;                           // element base index
  int n = i >> 7;
  int j = i & 127;
  float di = dinv[n];
  float w2 = di * di;
  float4 acc = *(float4*)(out + i);
  float4 hv  = *(const float4*)(h + i);
  float4 bv  = *(const float4*)(bias + j);
  float v[4];
  v[0] = acc.x + hv.x * w2 + bv.x;
  v[1] = acc.y + hv.y * w2 + bv.y;
  v[2] = acc.z + hv.z * w2 + bv.z;
  v[3] = acc.w + hv.w * w2 + bv.w;
#pragma unroll
  for (int q = 0; q < 4; ++q) {
    float r = fmaxf(v[q], 0.f);
    unsigned int bits = threefry_bits((unsigned int)(i + q));
    float u = __uint_as_float((bits >> 9) | 0x3f800000u) - 1.0f;
    v[q] = (u < 0.5f) ? r * 2.0f : 0.0f;
  }
  float4 res = make_float4(v[0], v[1], v[2], v[3]);
  *(float4*)(out + i) = res;
}

extern "C" void kernel_launch(void* const* d_in, const int* in_sizes, int n_in,
                              void* d_out, int out_size, void* d_ws, size_t ws_size,
                              hipStream_t stream) {
  const float* x    = (const float*)d_in[0];
  const int*   ei   = (const int*)d_in[1];
  const float* w    = (const float*)d_in[2];
  const float* bias = (const float*)d_in[3];
  float* out = (float*)d_out;

  float* h  = (float*)d_ws;                                   // N*D floats = 51.2 MB
  int*  deg = (int*)((char*)d_ws + (size_t)N_NODES * D * 4);  // N ints

  hipMemsetAsync(out, 0, (size_t)N_NODES * D * 4, stream);
  hipMemsetAsync(deg, 0, (size_t)N_NODES * 4, stream);

  k_deg<<<(E_EDGES + 255) / 256, 256, 0, stream>>>(ei + E_EDGES, deg);
  k_dinv<<<(N_NODES + 255) / 256, 256, 0, stream>>>(deg);
  k_gemm<<<N_NODES / 32, 256, 0, stream>>>(x, w, h);
  const float* dinv = (const float*)deg;
  k_scatter<<<(E_EDGES * 32) / 256, 256, 0, stream>>>(ei, h, dinv, out);
  k_final<<<(N_NODES * D / 4) / 256, 256, 0, stream>>>(out, h, dinv, bias);
}

// Round 3
// 469.731 us; speedup vs baseline: 6.2140x; 6.2140x over previous
//
#include <hip/hip_runtime.h>

#define N_NODES 100000
#define E_EDGES 1600000
#define D 128

// ---------- threefry2x32, key=(0,42), ctr=(0,i); JAX partitionable 32-bit: x0^x1 ----------
__device__ __forceinline__ unsigned int rotl32(unsigned int x, int r) {
  return (x << r) | (x >> (32 - r));
}

__device__ __forceinline__ unsigned int threefry_bits(unsigned int ctr) {
  const unsigned int ks0 = 0u, ks1 = 42u;
  const unsigned int ks2 = ks0 ^ ks1 ^ 0x1BD11BDAu;
  unsigned int x0 = ks0;
  unsigned int x1 = ctr + ks1;
#define TF_ROUND(R) { x0 += x1; x1 = rotl32(x1, R); x1 ^= x0; }
  TF_ROUND(13) TF_ROUND(15) TF_ROUND(26) TF_ROUND(6)
  x0 += ks1; x1 += ks2 + 1u;
  TF_ROUND(17) TF_ROUND(29) TF_ROUND(16) TF_ROUND(24)
  x0 += ks2; x1 += ks0 + 2u;
  TF_ROUND(13) TF_ROUND(15) TF_ROUND(26) TF_ROUND(6)
  x0 += ks0; x1 += ks1 + 3u;
  TF_ROUND(17) TF_ROUND(29) TF_ROUND(16) TF_ROUND(24)
  x0 += ks1; x1 += ks2 + 4u;
  TF_ROUND(13) TF_ROUND(15) TF_ROUND(26) TF_ROUND(6)
  x0 += ks2; x1 += ks0 + 5u;
#undef TF_ROUND
  return x0 ^ x1;
}

// ---------- degree histogram over dst ----------
__global__ __launch_bounds__(256) void k_deg(const int* __restrict__ dst,
                                             int* __restrict__ deg) {
  int e = blockIdx.x * 256 + threadIdx.x;
  if (e < E_EDGES) atomicAdd(&deg[dst[e]], 1);
}

// ---------- exclusive scan of deg, 3 kernels ----------
// s1: per-block (1024 elems) exclusive scan -> part, block totals -> bsum
__global__ __launch_bounds__(256) void k_scan1(const int* __restrict__ deg,
                                               int* __restrict__ part,
                                               int* __restrict__ bsum) {
  __shared__ int sm[256];
  int t = threadIdx.x, b = blockIdx.x;
  int base = b * 1024 + t * 4;
  int v[4]; int s = 0;
#pragma unroll
  for (int q = 0; q < 4; ++q) { v[q] = (base + q < N_NODES) ? deg[base + q] : 0; s += v[q]; }
  sm[t] = s; __syncthreads();
  for (int off = 1; off < 256; off <<= 1) {
    int x = (t >= off) ? sm[t - off] : 0;
    __syncthreads();
    sm[t] += x;
    __syncthreads();
  }
  int run = sm[t] - s;  // exclusive prefix of this thread within block
#pragma unroll
  for (int q = 0; q < 4; ++q) {
    if (base + q < N_NODES) part[base + q] = run;
    run += v[q];
  }
  if (t == 255) bsum[b] = sm[255];
}

// s2: exclusive scan of block sums (<=128), in place
__global__ __launch_bounds__(128) void k_scan2(int* __restrict__ bsum, int nblk) {
  __shared__ int sm[128];
  int t = threadIdx.x;
  int orig = (t < nblk) ? bsum[t] : 0;
  sm[t] = orig; __syncthreads();
  for (int off = 1; off < 128; off <<= 1) {
    int x = (t >= off) ? sm[t - off] : 0;
    __syncthreads();
    sm[t] += x;
    __syncthreads();
  }
  if (t < nblk) bsum[t] = sm[t] - orig;
}

// s3: rowptr = part + bsum[block]; also cursor copy; rowptr[N]=E; dinv in place
__global__ __launch_bounds__(256) void k_scan3(const int* __restrict__ part,
                                               const int* __restrict__ bsum,
                                               int* __restrict__ rowptr,
                                               int* __restrict__ cursor,
                                               int* __restrict__ deg) {
  int t = threadIdx.x, b = blockIdx.x;
  int off = bsum[b];
  int base = b * 1024 + t * 4;
#pragma unroll
  for (int q = 0; q < 4; ++q) {
    int i = base + q;
    if (i < N_NODES) {
      int r = part[i] + off;
      rowptr[i] = r;
      cursor[i] = r;
      // fold dinv here: deg -> float bits of rsqrt(deg+1)
      deg[i] = __float_as_int(rsqrtf((float)(deg[i] + 1)));
    }
  }
  if (b == 0 && t == 0) rowptr[N_NODES] = E_EDGES;
}

// ---------- fill CSR: srcs sorted by dst ----------
__global__ __launch_bounds__(256) void k_fill(const int* __restrict__ ei,
                                              int* __restrict__ cursor,
                                              int* __restrict__ srcs) {
  int e = blockIdx.x * 256 + threadIdx.x;
  if (e < E_EDGES) {
    int s = ei[e];
    int d = ei[E_EDGES + e];
    int pos = atomicAdd(&cursor[d], 1);
    srcs[pos] = s;
  }
}

// ---------- h = x @ W ; tile 32 rows x 128 cols ----------
__global__ __launch_bounds__(256) void k_gemm(const float* __restrict__ x,
                                              const float* __restrict__ w,
                                              float* __restrict__ h) {
  __shared__ float Ws[64 * 128];
  __shared__ float Xs[32 * 68];
  const int t  = threadIdx.x;
  const int tx = t & 31;
  const int ty = t >> 5;
  const int row0 = blockIdx.x * 32;
  float4 acc[4];
  acc[0] = acc[1] = acc[2] = acc[3] = make_float4(0.f, 0.f, 0.f, 0.f);

  for (int kt = 0; kt < 2; ++kt) {
    const float4* wsrc = (const float4*)(w + kt * 64 * 128);
    float4* wdst = (float4*)Ws;
#pragma unroll
    for (int i = 0; i < 8; ++i) wdst[t + i * 256] = wsrc[t + i * 256];
#pragma unroll
    for (int i = 0; i < 2; ++i) {
      int idx = t + i * 256;
      int r   = idx >> 4;
      int c4  = idx & 15;
      float4 v = *(const float4*)(x + (long long)(row0 + r) * D + kt * 64 + c4 * 4);
      *(float4*)(&Xs[r * 68 + c4 * 4]) = v;
    }
    __syncthreads();
#pragma unroll 8
    for (int k = 0; k < 64; ++k) {
      float4 wv = *(const float4*)(&Ws[k * 128 + tx * 4]);
#pragma unroll
      for (int i = 0; i < 4; ++i) {
        float xv = Xs[(ty * 4 + i) * 68 + k];
        acc[i].x += xv * wv.x; acc[i].y += xv * wv.y;
        acc[i].z += xv * wv.z; acc[i].w += xv * wv.w;
      }
    }
    __syncthreads();
  }
#pragma unroll
  for (int i = 0; i < 4; ++i) {
    int r = row0 + ty * 4 + i;
    *(float4*)(h + (long long)r * D + tx * 4) = acc[i];
  }
}

// ---------- aggregate (gather-side, atomic-free) + fused epilogue ----------
// one wave per node; lane holds cols {2*lane, 2*lane+1}
__global__ __launch_bounds__(256) void k_agg(const int* __restrict__ rowptr,
                                             const int* __restrict__ srcs,
                                             const float* __restrict__ dinv,
                                             const float* __restrict__ h,
                                             const float* __restrict__ bias,
                                             float* __restrict__ out) {
  int lane = threadIdx.x & 63;
  int n = blockIdx.x * 4 + (threadIdx.x >> 6);   // grid = N/4 exactly
  const float2* h2 = (const float2*)h;
  float dn = dinv[n];
  int e  = rowptr[n];
  int e1 = rowptr[n + 1];
  float2 acc = make_float2(0.f, 0.f);
  // unroll by 2 for two independent gather chains
  for (; e + 1 < e1; e += 2) {
    int s0 = srcs[e];
    int s1 = srcs[e + 1];
    float w0 = dinv[s0] * dn;
    float w1 = dinv[s1] * dn;
    float2 a = h2[(long long)s0 * 64 + lane];
    float2 b = h2[(long long)s1 * 64 + lane];
    acc.x += a.x * w0 + b.x * w1;
    acc.y += a.y * w0 + b.y * w1;
  }
  if (e < e1) {
    int s0 = srcs[e];
    float w0 = dinv[s0] * dn;
    float2 a = h2[(long long)s0 * 64 + lane];
    acc.x += a.x * w0;
    acc.y += a.y * w0;
  }
  // self loop
  float2 hs = h2[(long long)n * 64 + lane];
  acc.x += hs.x * dn * dn;
  acc.y += hs.y * dn * dn;
  // bias + relu
  float2 bb = ((const float2*)bias)[lane];
  float r0 = fmaxf(acc.x + bb.x, 0.f);
  float r1 = fmaxf(acc.y + bb.y, 0.f);
  // dropout
  unsigned int i0 = (unsigned int)n * 128u + (unsigned int)lane * 2u;
  unsigned int b0 = threefry_bits(i0);
  unsigned int b1 = threefry_bits(i0 + 1u);
  float u0 = __uint_as_float((b0 >> 9) | 0x3f800000u) - 1.0f;
  float u1 = __uint_as_float((b1 >> 9) | 0x3f800000u) - 1.0f;
  float2 res;
  res.x = (u0 < 0.5f) ? r0 * 2.0f : 0.0f;
  res.y = (u1 < 0.5f) ? r1 * 2.0f : 0.0f;
  ((float2*)out)[(long long)n * 64 + lane] = res;
}

extern "C" void kernel_launch(void* const* d_in, const int* in_sizes, int n_in,
                              void* d_out, int out_size, void* d_ws, size_t ws_size,
                              hipStream_t stream) {
  const float* x    = (const float*)d_in[0];
  const int*   ei   = (const int*)d_in[1];
  const float* w    = (const float*)d_in[2];
  const float* bias = (const float*)d_in[3];
  float* out = (float*)d_out;

  // workspace carve (all 4-byte elems)
  char* p = (char*)d_ws;
  float* h      = (float*)p;                 p += (size_t)N_NODES * D * 4;   // 51.2 MB
  int*   deg    = (int*)p;                   p += (size_t)N_NODES * 4;       // dinv after scan3
  int*   rowptr = (int*)p;                   p += (size_t)(N_NODES + 1) * 4;
  int*   cursor = (int*)p;                   p += (size_t)N_NODES * 4;
  int*   part   = (int*)p;                   p += (size_t)N_NODES * 4;
  int*   bsum   = (int*)p;                   p += 128 * 4;
  int*   srcs   = (int*)p;                   p += (size_t)E_EDGES * 4;       // 6.4 MB

  const int NBLK_SCAN = (N_NODES + 1023) / 1024;  // 98

  hipMemsetAsync(deg, 0, (size_t)N_NODES * 4, stream);

  k_deg<<<(E_EDGES + 255) / 256, 256, 0, stream>>>(ei + E_EDGES, deg);
  k_scan1<<<NBLK_SCAN, 256, 0, stream>>>(deg, part, bsum);
  k_scan2<<<1, 128, 0, stream>>>(bsum, NBLK_SCAN);
  k_scan3<<<NBLK_SCAN, 256, 0, stream>>>(part, bsum, rowptr, cursor, deg);
  k_gemm<<<N_NODES / 32, 256, 0, stream>>>(x, w, h);
  k_fill<<<(E_EDGES + 255) / 256, 256, 0, stream>>>(ei, cursor, srcs);
  const float* dinv = (const float*)deg;
  k_agg<<<N_NODES / 4, 256, 0, stream>>>(rowptr, srcs, dinv, h, bias, out);
}

// Round 4
// 410.376 us; speedup vs baseline: 7.1128x; 1.1446x over previous
//
#include <hip/hip_runtime.h>

#define N_NODES 100000
#define E_EDGES 1600000
#define D 128

typedef __attribute__((ext_vector_type(8))) short short8;
typedef __attribute__((ext_vector_type(4))) float f32x4;

// ---------- threefry2x32, key=(0,42), ctr=(0,i); JAX partitionable 32-bit: x0^x1 ----------
__device__ __forceinline__ unsigned int rotl32(unsigned int x, int r) {
  return (x << r) | (x >> (32 - r));
}

__device__ __forceinline__ unsigned int threefry_bits(unsigned int ctr) {
  const unsigned int ks0 = 0u, ks1 = 42u;
  const unsigned int ks2 = ks0 ^ ks1 ^ 0x1BD11BDAu;
  unsigned int x0 = ks0;
  unsigned int x1 = ctr + ks1;
#define TF_ROUND(R) { x0 += x1; x1 = rotl32(x1, R); x1 ^= x0; }
  TF_ROUND(13) TF_ROUND(15) TF_ROUND(26) TF_ROUND(6)
  x0 += ks1; x1 += ks2 + 1u;
  TF_ROUND(17) TF_ROUND(29) TF_ROUND(16) TF_ROUND(24)
  x0 += ks2; x1 += ks0 + 2u;
  TF_ROUND(13) TF_ROUND(15) TF_ROUND(26) TF_ROUND(6)
  x0 += ks0; x1 += ks1 + 3u;
  TF_ROUND(17) TF_ROUND(29) TF_ROUND(16) TF_ROUND(24)
  x0 += ks1; x1 += ks2 + 4u;
  TF_ROUND(13) TF_ROUND(15) TF_ROUND(26) TF_ROUND(6)
  x0 += ks2; x1 += ks0 + 5u;
#undef TF_ROUND
  return x0 ^ x1;
}

__device__ __forceinline__ unsigned short f2bf(float f) {
  unsigned int u = __float_as_uint(f);
  u = (u + 0x7FFFu + ((u >> 16) & 1u)) >> 16;   // RNE
  return (unsigned short)u;
}
__device__ __forceinline__ float bf2f_lo(unsigned int v) {
  return __uint_as_float(v << 16);
}
__device__ __forceinline__ float bf2f_hi(unsigned int v) {
  return __uint_as_float(v & 0xFFFF0000u);
}

// ---------- degree histogram over dst ----------
__global__ __launch_bounds__(256) void k_deg(const int* __restrict__ dst,
                                             int* __restrict__ deg) {
  int e = blockIdx.x * 256 + threadIdx.x;
  if (e < E_EDGES) atomicAdd(&deg[dst[e]], 1);
}

// ---------- exclusive scan of deg, 3 kernels ----------
__global__ __launch_bounds__(256) void k_scan1(const int* __restrict__ deg,
                                               int* __restrict__ part,
                                               int* __restrict__ bsum) {
  __shared__ int sm[256];
  int t = threadIdx.x, b = blockIdx.x;
  int base = b * 1024 + t * 4;
  int v[4]; int s = 0;
#pragma unroll
  for (int q = 0; q < 4; ++q) { v[q] = (base + q < N_NODES) ? deg[base + q] : 0; s += v[q]; }
  sm[t] = s; __syncthreads();
  for (int off = 1; off < 256; off <<= 1) {
    int x = (t >= off) ? sm[t - off] : 0;
    __syncthreads();
    sm[t] += x;
    __syncthreads();
  }
  int run = sm[t] - s;
#pragma unroll
  for (int q = 0; q < 4; ++q) {
    if (base + q < N_NODES) part[base + q] = run;
    run += v[q];
  }
  if (t == 255) bsum[b] = sm[255];
}

__global__ __launch_bounds__(128) void k_scan2(int* __restrict__ bsum, int nblk) {
  __shared__ int sm[128];
  int t = threadIdx.x;
  int orig = (t < nblk) ? bsum[t] : 0;
  sm[t] = orig; __syncthreads();
  for (int off = 1; off < 128; off <<= 1) {
    int x = (t >= off) ? sm[t - off] : 0;
    __syncthreads();
    sm[t] += x;
    __syncthreads();
  }
  if (t < nblk) bsum[t] = sm[t] - orig;
}

__global__ __launch_bounds__(256) void k_scan3(const int* __restrict__ part,
                                               const int* __restrict__ bsum,
                                               int* __restrict__ rowptr,
                                               int* __restrict__ cursor,
                                               int* __restrict__ deg) {
  int t = threadIdx.x, b = blockIdx.x;
  int off = bsum[b];
  int base = b * 1024 + t * 4;
#pragma unroll
  for (int q = 0; q < 4; ++q) {
    int i = base + q;
    if (i < N_NODES) {
      int r = part[i] + off;
      rowptr[i] = r;
      cursor[i] = r;
      deg[i] = __float_as_int(rsqrtf((float)(deg[i] + 1)));  // dinv in place
    }
  }
  if (b == 0 && t == 0) rowptr[N_NODES] = E_EDGES;
}

// ---------- fill CSR: (src, dinv[src]) pairs sorted by dst ----------
__global__ __launch_bounds__(256) void k_fill(const int* __restrict__ ei,
                                              const int* __restrict__ dinv_bits,
                                              int* __restrict__ cursor,
                                              int2* __restrict__ srcw) {
  int e = blockIdx.x * 256 + threadIdx.x;
  if (e < E_EDGES) {
    int s = ei[e];
    int d = ei[E_EDGES + e];
    int pos = atomicAdd(&cursor[d], 1);
    srcw[pos] = make_int2(s, dinv_bits[s]);
  }
}

// ---------- h = bf16(x @ W) via MFMA 16x16x32 ----------
// block: 256 thr = 4 waves; 64 node-rows per block; K=128 fully staged in LDS.
__global__ __launch_bounds__(256) void k_gemm(const float* __restrict__ x,
                                              const float* __restrict__ w,
                                              unsigned short* __restrict__ h) {
  __shared__ unsigned short Wl[128 * 136];  // [n][k], pad 136 to break conflicts
  __shared__ unsigned short Xl[64 * 136];   // [m][k]
  const int t = threadIdx.x;
  const int row0 = blockIdx.x * 64;

  // stage W: read [k][n] fp32 coalesced, write bf16 transposed [n][k]
  const float4* w4 = (const float4*)w;
#pragma unroll
  for (int i = 0; i < 16; ++i) {
    int id = t + i * 256;          // 0..4095
    int k  = id >> 5;              // 0..127
    int n4 = id & 31;              // 0..31
    float4 v = w4[k * 32 + n4];
    Wl[(n4 * 4 + 0) * 136 + k] = f2bf(v.x);
    Wl[(n4 * 4 + 1) * 136 + k] = f2bf(v.y);
    Wl[(n4 * 4 + 2) * 136 + k] = f2bf(v.z);
    Wl[(n4 * 4 + 3) * 136 + k] = f2bf(v.w);
  }
  // stage X: 64 rows x 128 k
  const float4* x4 = (const float4*)x;
#pragma unroll
  for (int i = 0; i < 8; ++i) {
    int id = t + i * 256;          // 0..2047
    int r  = id >> 5;              // 0..63
    int c4 = id & 31;              // 0..31
    int row = row0 + r; if (row >= N_NODES) row = N_NODES - 1;
    float4 v = x4[(long long)row * 32 + c4];
    ushort4 p;
    p.x = f2bf(v.x); p.y = f2bf(v.y); p.z = f2bf(v.z); p.w = f2bf(v.w);
    *(ushort4*)&Xl[r * 136 + c4 * 4] = p;
  }
  __syncthreads();

  const int wv   = t >> 6;       // wave 0..3 -> rows m0..m0+15
  const int l    = t & 63;
  const int quad = l >> 4;
  const int ln16 = l & 15;
  const int m0   = wv * 16;

  short8 a[4];
#pragma unroll
  for (int kt = 0; kt < 4; ++kt)
    a[kt] = *(const short8*)&Xl[(m0 + ln16) * 136 + kt * 32 + quad * 8];

#pragma unroll
  for (int nt = 0; nt < 8; ++nt) {
    f32x4 acc = {0.f, 0.f, 0.f, 0.f};
#pragma unroll
    for (int kt = 0; kt < 4; ++kt) {
      short8 b = *(const short8*)&Wl[(nt * 16 + ln16) * 136 + kt * 32 + quad * 8];
      acc = __builtin_amdgcn_mfma_f32_16x16x32_bf16(a[kt], b, acc, 0, 0, 0);
    }
    // C/D layout: col = l&15, row = quad*4 + reg
#pragma unroll
    for (int r = 0; r < 4; ++r) {
      int row = row0 + m0 + quad * 4 + r;
      if (row < N_NODES)
        h[(long long)row * D + nt * 16 + ln16] = f2bf(acc[r]);
    }
  }
}

// ---------- aggregate (gather-side, bf16 h) + fused epilogue ----------
// wave per node; half-wave per edge (2 edges/iter); lane gathers 8B = 4 bf16 cols
__global__ __launch_bounds__(256) void k_agg(const int* __restrict__ rowptr,
                                             const int2* __restrict__ srcw,
                                             const float* __restrict__ dinv,
                                             const unsigned short* __restrict__ h,
                                             const float* __restrict__ bias,
                                             float* __restrict__ out) {
  const int t = threadIdx.x;
  const int n = blockIdx.x * 4 + (t >> 6);
  const int lane = t & 63;
  const int half = lane >> 5;
  const int li   = lane & 31;
  const uint2* hq = (const uint2*)h;   // 32 uint2 per row (4 bf16 each)
  float dn = dinv[n];
  int e1 = rowptr[n + 1];
  float acc0 = 0.f, acc1 = 0.f, acc2 = 0.f, acc3 = 0.f;
  for (int e = rowptr[n] + half; e < e1; e += 2) {
    int2 sw = srcw[e];
    float wgt = __int_as_float(sw.y) * dn;
    uint2 v = hq[(long long)sw.x * 32 + li];
    acc0 = fmaf(bf2f_lo(v.x), wgt, acc0);
    acc1 = fmaf(bf2f_hi(v.x), wgt, acc1);
    acc2 = fmaf(bf2f_lo(v.y), wgt, acc2);
    acc3 = fmaf(bf2f_hi(v.y), wgt, acc3);
  }
  // combine halves (cols li*4..li*4+3 now complete in every lane)
  acc0 += __shfl_xor(acc0, 32);
  acc1 += __shfl_xor(acc1, 32);
  acc2 += __shfl_xor(acc2, 32);
  acc3 += __shfl_xor(acc3, 32);
  // each lane finalizes 2 cols: c0 = li*4 + half*2
  float a0 = (half == 0) ? acc0 : acc2;
  float a1 = (half == 0) ? acc1 : acc3;
  // self loop
  unsigned int hv = ((const unsigned int*)h)[(long long)n * 64 + li * 2 + half];
  float w2 = dn * dn;
  a0 = fmaf(bf2f_lo(hv), w2, a0);
  a1 = fmaf(bf2f_hi(hv), w2, a1);
  // bias + relu
  float2 bb = ((const float2*)bias)[li * 2 + half];
  float r0 = fmaxf(a0 + bb.x, 0.f);
  float r1 = fmaxf(a1 + bb.y, 0.f);
  // dropout
  unsigned int i0 = (unsigned int)n * 128u + (unsigned int)(li * 4 + half * 2);
  unsigned int b0 = threefry_bits(i0);
  unsigned int b1 = threefry_bits(i0 + 1u);
  float u0 = __uint_as_float((b0 >> 9) | 0x3f800000u) - 1.0f;
  float u1 = __uint_as_float((b1 >> 9) | 0x3f800000u) - 1.0f;
  float2 res;
  res.x = (u0 < 0.5f) ? r0 * 2.0f : 0.0f;
  res.y = (u1 < 0.5f) ? r1 * 2.0f : 0.0f;
  ((float2*)out)[(long long)n * 64 + li * 2 + half] = res;
}

extern "C" void kernel_launch(void* const* d_in, const int* in_sizes, int n_in,
                              void* d_out, int out_size, void* d_ws, size_t ws_size,
                              hipStream_t stream) {
  const float* x    = (const float*)d_in[0];
  const int*   ei   = (const int*)d_in[1];
  const float* w    = (const float*)d_in[2];
  const float* bias = (const float*)d_in[3];
  float* out = (float*)d_out;

  char* p = (char*)d_ws;
  unsigned short* h = (unsigned short*)p;   p += (size_t)N_NODES * D * 2;  // 25.6 MB
  int*  deg    = (int*)p;                   p += (size_t)N_NODES * 4;      // dinv after scan3
  int*  rowptr = (int*)p;                   p += (size_t)(N_NODES + 1) * 4;
  int*  cursor = (int*)p;                   p += (size_t)N_NODES * 4;
  int*  part   = (int*)p;                   p += (size_t)N_NODES * 4;
  int*  bsum   = (int*)p;                   p += 128 * 4;
  int2* srcw   = (int2*)p;                  p += (size_t)E_EDGES * 8;      // 12.8 MB

  const int NBLK_SCAN = (N_NODES + 1023) / 1024;  // 98

  hipMemsetAsync(deg, 0, (size_t)N_NODES * 4, stream);

  k_deg<<<(E_EDGES + 255) / 256, 256, 0, stream>>>(ei + E_EDGES, deg);
  k_scan1<<<NBLK_SCAN, 256, 0, stream>>>(deg, part, bsum);
  k_scan2<<<1, 128, 0, stream>>>(bsum, NBLK_SCAN);
  k_scan3<<<NBLK_SCAN, 256, 0, stream>>>(part, bsum, rowptr, cursor, deg);
  k_gemm<<<(N_NODES + 63) / 64, 256, 0, stream>>>(x, w, h);
  k_fill<<<(E_EDGES + 255) / 256, 256, 0, stream>>>(ei, deg, cursor, srcw);
  const float* dinv = (const float*)deg;
  k_agg<<<N_NODES / 4, 256, 0, stream>>>(rowptr, srcw, dinv, h, bias, out);
}

// Round 5
// 351.932 us; speedup vs baseline: 8.2939x; 1.1661x over previous
//
#include <hip/hip_runtime.h>

#define N_NODES 100000
#define E_EDGES 1600000
#define D 128
#define NRANGE 8
#define RSIZE 12500        // nodes per range (N/8)
#define FCHUNK 2048        // edges per fill block

typedef __attribute__((ext_vector_type(8))) short short8;
typedef __attribute__((ext_vector_type(4))) float f32x4;

// ---------- threefry2x32, key=(0,42), ctr=(0,i); JAX partitionable 32-bit: x0^x1 ----------
__device__ __forceinline__ unsigned int rotl32(unsigned int x, int r) {
  return (x << r) | (x >> (32 - r));
}

__device__ __forceinline__ unsigned int threefry_bits(unsigned int ctr) {
  const unsigned int ks0 = 0u, ks1 = 42u;
  const unsigned int ks2 = ks0 ^ ks1 ^ 0x1BD11BDAu;
  unsigned int x0 = ks0;
  unsigned int x1 = ctr + ks1;
#define TF_ROUND(R) { x0 += x1; x1 = rotl32(x1, R); x1 ^= x0; }
  TF_ROUND(13) TF_ROUND(15) TF_ROUND(26) TF_ROUND(6)
  x0 += ks1; x1 += ks2 + 1u;
  TF_ROUND(17) TF_ROUND(29) TF_ROUND(16) TF_ROUND(24)
  x0 += ks2; x1 += ks0 + 2u;
  TF_ROUND(13) TF_ROUND(15) TF_ROUND(26) TF_ROUND(6)
  x0 += ks0; x1 += ks1 + 3u;
  TF_ROUND(17) TF_ROUND(29) TF_ROUND(16) TF_ROUND(24)
  x0 += ks1; x1 += ks2 + 4u;
  TF_ROUND(13) TF_ROUND(15) TF_ROUND(26) TF_ROUND(6)
  x0 += ks2; x1 += ks0 + 5u;
#undef TF_ROUND
  return x0 ^ x1;
}

__device__ __forceinline__ unsigned short f2bf(float f) {
  unsigned int u = __float_as_uint(f);
  u = (u + 0x7FFFu + ((u >> 16) & 1u)) >> 16;   // RNE
  return (unsigned short)u;
}
__device__ __forceinline__ float bf2f_lo(unsigned int v) {
  return __uint_as_float(v << 16);
}
__device__ __forceinline__ float bf2f_hi(unsigned int v) {
  return __uint_as_float(v & 0xFFFF0000u);
}

// ---------- degree histogram over dst ----------
__global__ __launch_bounds__(256) void k_deg(const int* __restrict__ dst,
                                             int* __restrict__ deg) {
  int e = blockIdx.x * 256 + threadIdx.x;
  if (e < E_EDGES) atomicAdd(&deg[dst[e]], 1);
}

// ---------- exclusive scan of deg, 3 kernels ----------
__global__ __launch_bounds__(256) void k_scan1(const int* __restrict__ deg,
                                               int* __restrict__ part,
                                               int* __restrict__ bsum) {
  __shared__ int sm[256];
  int t = threadIdx.x, b = blockIdx.x;
  int base = b * 1024 + t * 4;
  int v[4]; int s = 0;
#pragma unroll
  for (int q = 0; q < 4; ++q) { v[q] = (base + q < N_NODES) ? deg[base + q] : 0; s += v[q]; }
  sm[t] = s; __syncthreads();
  for (int off = 1; off < 256; off <<= 1) {
    int x = (t >= off) ? sm[t - off] : 0;
    __syncthreads();
    sm[t] += x;
    __syncthreads();
  }
  int run = sm[t] - s;
#pragma unroll
  for (int q = 0; q < 4; ++q) {
    if (base + q < N_NODES) part[base + q] = run;
    run += v[q];
  }
  if (t == 255) bsum[b] = sm[255];
}

__global__ __launch_bounds__(128) void k_scan2(int* __restrict__ bsum, int nblk) {
  __shared__ int sm[128];
  int t = threadIdx.x;
  int orig = (t < nblk) ? bsum[t] : 0;
  sm[t] = orig; __syncthreads();
  for (int off = 1; off < 128; off <<= 1) {
    int x = (t >= off) ? sm[t - off] : 0;
    __syncthreads();
    sm[t] += x;
    __syncthreads();
  }
  if (t < nblk) bsum[t] = sm[t] - orig;
}

__global__ __launch_bounds__(256) void k_scan3(const int* __restrict__ part,
                                               const int* __restrict__ bsum,
                                               int* __restrict__ rowptr,
                                               int* __restrict__ cursor,
                                               int* __restrict__ deg) {
  int t = threadIdx.x, b = blockIdx.x;
  int off = bsum[b];
  int base = b * 1024 + t * 4;
#pragma unroll
  for (int q = 0; q < 4; ++q) {
    int i = base + q;
    if (i < N_NODES) {
      int r = part[i] + off;
      rowptr[i] = r;
      cursor[i] = r;
      deg[i] = __float_as_int(rsqrtf((float)(deg[i] + 1)));  // dinv in place
    }
  }
  if (b == 0 && t == 0) rowptr[N_NODES] = E_EDGES;
}

// ---------- fill CSR, XCD-range partitioned ----------
// 8 blocks share each edge chunk; block handles range (blockIdx & 7). Under the
// round-robin block->XCD mapping all writers of one CSR slice (1.6 MB, fits one
// XCD L2) sit on the same XCD -> lines fully aggregated before writeback.
__global__ __launch_bounds__(256) void k_fill(const int* __restrict__ ei,
                                              const int* __restrict__ dinv_bits,
                                              int* __restrict__ cursor,
                                              int2* __restrict__ srcw) {
  const int r     = blockIdx.x & 7;
  const int base  = (blockIdx.x >> 3) * FCHUNK;
  const int lo    = r * RSIZE;
  const int hi    = lo + RSIZE;
#pragma unroll
  for (int i = 0; i < FCHUNK / 256; ++i) {
    int e = base + i * 256 + threadIdx.x;
    if (e < E_EDGES) {
      int d = ei[E_EDGES + e];
      if (d >= lo && d < hi) {
        int s = ei[e];
        int pos = atomicAdd(&cursor[d], 1);
        srcw[pos] = make_int2(s, dinv_bits[s]);
      }
    }
  }
}

// ---------- h = bf16(x @ W) via MFMA 16x16x32 ----------
__global__ __launch_bounds__(256) void k_gemm(const float* __restrict__ x,
                                              const float* __restrict__ w,
                                              unsigned short* __restrict__ h) {
  __shared__ unsigned short Wl[128 * 136];
  __shared__ unsigned short Xl[64 * 136];
  const int t = threadIdx.x;
  const int row0 = blockIdx.x * 64;

  const float4* w4 = (const float4*)w;
#pragma unroll
  for (int i = 0; i < 16; ++i) {
    int id = t + i * 256;
    int k  = id >> 5;
    int n4 = id & 31;
    float4 v = w4[k * 32 + n4];
    Wl[(n4 * 4 + 0) * 136 + k] = f2bf(v.x);
    Wl[(n4 * 4 + 1) * 136 + k] = f2bf(v.y);
    Wl[(n4 * 4 + 2) * 136 + k] = f2bf(v.z);
    Wl[(n4 * 4 + 3) * 136 + k] = f2bf(v.w);
  }
  const float4* x4 = (const float4*)x;
#pragma unroll
  for (int i = 0; i < 8; ++i) {
    int id = t + i * 256;
    int r  = id >> 5;
    int c4 = id & 31;
    int row = row0 + r; if (row >= N_NODES) row = N_NODES - 1;
    float4 v = x4[(long long)row * 32 + c4];
    ushort4 p;
    p.x = f2bf(v.x); p.y = f2bf(v.y); p.z = f2bf(v.z); p.w = f2bf(v.w);
    *(ushort4*)&Xl[r * 136 + c4 * 4] = p;
  }
  __syncthreads();

  const int wv   = t >> 6;
  const int l    = t & 63;
  const int quad = l >> 4;
  const int ln16 = l & 15;
  const int m0   = wv * 16;

  short8 a[4];
#pragma unroll
  for (int kt = 0; kt < 4; ++kt)
    a[kt] = *(const short8*)&Xl[(m0 + ln16) * 136 + kt * 32 + quad * 8];

#pragma unroll
  for (int nt = 0; nt < 8; ++nt) {
    f32x4 acc = {0.f, 0.f, 0.f, 0.f};
#pragma unroll
    for (int kt = 0; kt < 4; ++kt) {
      short8 b = *(const short8*)&Wl[(nt * 16 + ln16) * 136 + kt * 32 + quad * 8];
      acc = __builtin_amdgcn_mfma_f32_16x16x32_bf16(a[kt], b, acc, 0, 0, 0);
    }
#pragma unroll
    for (int r = 0; r < 4; ++r) {
      int row = row0 + m0 + quad * 4 + r;
      if (row < N_NODES)
        h[(long long)row * D + nt * 16 + ln16] = f2bf(acc[r]);
    }
  }
}

// ---------- aggregate: quarter-wave per edge, uint4 gathers, fused epilogue ----------
__global__ __launch_bounds__(256) void k_agg(const int* __restrict__ rowptr,
                                             const int2* __restrict__ srcw,
                                             const float* __restrict__ dinv,
                                             const unsigned short* __restrict__ h,
                                             const float* __restrict__ bias,
                                             float* __restrict__ out) {
  const int t = threadIdx.x;
  const int n = blockIdx.x * 4 + (t >> 6);
  const int lane = t & 63;
  const int q  = lane >> 4;       // quarter 0..3
  const int li = lane & 15;       // lane-in-quarter; owns cols li*8..li*8+7
  const uint4* hq = (const uint4*)h;   // 16 uint4 per row
  float dn = dinv[n];
  int e1 = rowptr[n + 1];
  float acc[8];
#pragma unroll
  for (int j = 0; j < 8; ++j) acc[j] = 0.f;

  for (int e = rowptr[n] + q; e < e1; e += 4) {
    int2 sw = srcw[e];
    float wgt = __int_as_float(sw.y) * dn;
    uint4 v = hq[(long long)sw.x * 16 + li];
    acc[0] = fmaf(bf2f_lo(v.x), wgt, acc[0]);
    acc[1] = fmaf(bf2f_hi(v.x), wgt, acc[1]);
    acc[2] = fmaf(bf2f_lo(v.y), wgt, acc[2]);
    acc[3] = fmaf(bf2f_hi(v.y), wgt, acc[3]);
    acc[4] = fmaf(bf2f_lo(v.z), wgt, acc[4]);
    acc[5] = fmaf(bf2f_hi(v.z), wgt, acc[5]);
    acc[6] = fmaf(bf2f_lo(v.w), wgt, acc[6]);
    acc[7] = fmaf(bf2f_hi(v.w), wgt, acc[7]);
  }
  // combine quarters: after xor-16 and xor-32 every lane holds full col sums
#pragma unroll
  for (int j = 0; j < 8; ++j) {
    acc[j] += __shfl_xor(acc[j], 16);
    acc[j] += __shfl_xor(acc[j], 32);
  }
  // lane finalizes cols c0 = li*8 + q*2, c0+1
  float a0 = acc[q * 2];
  float a1 = acc[q * 2 + 1];
  // self loop
  unsigned int hv = ((const unsigned int*)h)[(long long)n * 64 + li * 4 + q];
  float w2 = dn * dn;
  a0 = fmaf(bf2f_lo(hv), w2, a0);
  a1 = fmaf(bf2f_hi(hv), w2, a1);
  // bias + relu
  float2 bb = ((const float2*)bias)[li * 4 + q];
  float r0 = fmaxf(a0 + bb.x, 0.f);
  float r1 = fmaxf(a1 + bb.y, 0.f);
  // dropout
  unsigned int i0 = (unsigned int)n * 128u + (unsigned int)(li * 8 + q * 2);
  unsigned int b0 = threefry_bits(i0);
  unsigned int b1 = threefry_bits(i0 + 1u);
  float u0 = __uint_as_float((b0 >> 9) | 0x3f800000u) - 1.0f;
  float u1 = __uint_as_float((b1 >> 9) | 0x3f800000u) - 1.0f;
  float2 res;
  res.x = (u0 < 0.5f) ? r0 * 2.0f : 0.0f;
  res.y = (u1 < 0.5f) ? r1 * 2.0f : 0.0f;
  ((float2*)out)[(long long)n * 64 + li * 4 + q] = res;
}

extern "C" void kernel_launch(void* const* d_in, const int* in_sizes, int n_in,
                              void* d_out, int out_size, void* d_ws, size_t ws_size,
                              hipStream_t stream) {
  const float* x    = (const float*)d_in[0];
  const int*   ei   = (const int*)d_in[1];
  const float* w    = (const float*)d_in[2];
  const float* bias = (const float*)d_in[3];
  float* out = (float*)d_out;

  char* p = (char*)d_ws;
  unsigned short* h = (unsigned short*)p;   p += (size_t)N_NODES * D * 2;  // 25.6 MB
  int*  deg    = (int*)p;                   p += (size_t)N_NODES * 4;      // dinv after scan3
  int*  rowptr = (int*)p;                   p += (size_t)(N_NODES + 1) * 4;
  int*  cursor = (int*)p;                   p += (size_t)N_NODES * 4;
  int*  part   = (int*)p;                   p += (size_t)N_NODES * 4;
  int*  bsum   = (int*)p;                   p += 128 * 4;
  int2* srcw   = (int2*)p;                  p += (size_t)E_EDGES * 8;      // 12.8 MB

  const int NBLK_SCAN = (N_NODES + 1023) / 1024;  // 98

  hipMemsetAsync(deg, 0, (size_t)N_NODES * 4, stream);

  k_deg<<<(E_EDGES + 255) / 256, 256, 0, stream>>>(ei + E_EDGES, deg);
  k_scan1<<<NBLK_SCAN, 256, 0, stream>>>(deg, part, bsum);
  k_scan2<<<1, 128, 0, stream>>>(bsum, NBLK_SCAN);
  k_scan3<<<NBLK_SCAN, 256, 0, stream>>>(part, bsum, rowptr, cursor, deg);
  k_gemm<<<(N_NODES + 63) / 64, 256, 0, stream>>>(x, w, h);
  const int FILL_BLKS = ((E_EDGES + FCHUNK - 1) / FCHUNK) * NRANGE;  // 782*8
  k_fill<<<FILL_BLKS, 256, 0, stream>>>(ei, deg, cursor, srcw);
  const float* dinv = (const float*)deg;
  k_agg<<<N_NODES / 4, 256, 0, stream>>>(rowptr, srcw, dinv, h, bias, out);
}

// Round 6
// 327.305 us; speedup vs baseline: 8.9180x; 1.0752x over previous
//
#include <hip/hip_runtime.h>

#define N_NODES 100000
#define E_EDGES 1600000
#define D 128
#define NRANGE 8
#define RSIZE 12500        // nodes per range (N/8)
#define FCHUNK 2048        // edges per fill block
#define PAD 136            // LDS row stride (ushorts): 272B = 16B-aligned, frag reads ~conflict-free
#define GEMM_BLKS 1563     // (N+63)/64
#define DEG_BLKS 6250      // E/256
#define NBLK_SCAN 98       // (N+1023)/1024

typedef __attribute__((ext_vector_type(8))) short short8;
typedef __attribute__((ext_vector_type(8))) unsigned short ushort8v;
typedef __attribute__((ext_vector_type(4))) float f32x4;

// ---------- threefry2x32, key=(0,42), ctr=(0,i); JAX partitionable 32-bit: x0^x1 ----------
__device__ __forceinline__ unsigned int rotl32(unsigned int x, int r) {
  return (x << r) | (x >> (32 - r));
}

__device__ __forceinline__ unsigned int threefry_bits(unsigned int ctr) {
  const unsigned int ks0 = 0u, ks1 = 42u;
  const unsigned int ks2 = ks0 ^ ks1 ^ 0x1BD11BDAu;
  unsigned int x0 = ks0;
  unsigned int x1 = ctr + ks1;
#define TF_ROUND(R) { x0 += x1; x1 = rotl32(x1, R); x1 ^= x0; }
  TF_ROUND(13) TF_ROUND(15) TF_ROUND(26) TF_ROUND(6)
  x0 += ks1; x1 += ks2 + 1u;
  TF_ROUND(17) TF_ROUND(29) TF_ROUND(16) TF_ROUND(24)
  x0 += ks2; x1 += ks0 + 2u;
  TF_ROUND(13) TF_ROUND(15) TF_ROUND(26) TF_ROUND(6)
  x0 += ks0; x1 += ks1 + 3u;
  TF_ROUND(17) TF_ROUND(29) TF_ROUND(16) TF_ROUND(24)
  x0 += ks1; x1 += ks2 + 4u;
  TF_ROUND(13) TF_ROUND(15) TF_ROUND(26) TF_ROUND(6)
  x0 += ks2; x1 += ks0 + 5u;
#undef TF_ROUND
  return x0 ^ x1;
}

__device__ __forceinline__ unsigned short f2bf(float f) {
  unsigned int u = __float_as_uint(f);
  u = (u + 0x7FFFu + ((u >> 16) & 1u)) >> 16;   // RNE
  return (unsigned short)u;
}
__device__ __forceinline__ float bf2f_lo(unsigned int v) {
  return __uint_as_float(v << 16);
}
__device__ __forceinline__ float bf2f_hi(unsigned int v) {
  return __uint_as_float(v & 0xFFFF0000u);
}

// ---------- fused: gemm (blocks 0..GEMM_BLKS-1) + deg histogram (rest) ----------
__global__ __launch_bounds__(256) void k_pre(const float* __restrict__ x,
                                             const float* __restrict__ w,
                                             unsigned short* __restrict__ h,
                                             const int* __restrict__ dst,
                                             int* __restrict__ deg) {
  __shared__ unsigned short Wl[128 * PAD];   // [n][k]
  __shared__ unsigned short Xl[64 * PAD];    // [m][k]
  const int t = threadIdx.x;

  if (blockIdx.x >= GEMM_BLKS) {
    int e = (blockIdx.x - GEMM_BLKS) * 256 + t;
    if (e < E_EDGES) atomicAdd(&deg[dst[e]], 1);
    return;
  }

  const int row0 = blockIdx.x * 64;

  // stage W: one ushort8 (16B) unit per lane-iter; unit u -> n = u&127, kg = u>>7.
  // inner j loop is coalesced across lanes (consecutive n); b128 LDS writes, no 16-way conflict.
#pragma unroll
  for (int i = 0; i < 8; ++i) {
    int u  = t + i * 256;        // 0..2047
    int n  = u & 127;
    int kg = u >> 7;             // 0..15
    ushort8v p;
#pragma unroll
    for (int j = 0; j < 8; ++j)
      p[j] = (short)f2bf(w[(kg * 8 + j) * D + n]);
    *(ushort8v*)&Wl[n * PAD + kg * 8] = p;
  }
  // stage X: 64 rows x 128 k
  const float4* x4 = (const float4*)x;
#pragma unroll
  for (int i = 0; i < 8; ++i) {
    int id = t + i * 256;
    int r  = id >> 5;
    int c4 = id & 31;
    int row = row0 + r; if (row >= N_NODES) row = N_NODES - 1;
    float4 v = x4[(long long)row * 32 + c4];
    ushort4 p;
    p.x = f2bf(v.x); p.y = f2bf(v.y); p.z = f2bf(v.z); p.w = f2bf(v.w);
    *(ushort4*)&Xl[r * PAD + c4 * 4] = p;
  }
  __syncthreads();

  const int wv   = t >> 6;
  const int l    = t & 63;
  const int quad = l >> 4;
  const int ln16 = l & 15;
  const int m0   = wv * 16;

  short8 a[4];
#pragma unroll
  for (int kt = 0; kt < 4; ++kt)
    a[kt] = *(const short8*)&Xl[(m0 + ln16) * PAD + kt * 32 + quad * 8];

#pragma unroll
  for (int nt = 0; nt < 8; ++nt) {
    f32x4 acc = {0.f, 0.f, 0.f, 0.f};
#pragma unroll
    for (int kt = 0; kt < 4; ++kt) {
      short8 b = *(const short8*)&Wl[(nt * 16 + ln16) * PAD + kt * 32 + quad * 8];
      acc = __builtin_amdgcn_mfma_f32_16x16x32_bf16(a[kt], b, acc, 0, 0, 0);
    }
#pragma unroll
    for (int r = 0; r < 4; ++r) {
      int row = row0 + m0 + quad * 4 + r;
      if (row < N_NODES)
        h[(long long)row * D + nt * 16 + ln16] = f2bf(acc[r]);
    }
  }
}

// ---------- scan stage 1: per-block (1024 elems) scan -> part, block totals -> bsum ----------
__global__ __launch_bounds__(256) void k_scan1(const int* __restrict__ deg,
                                               int* __restrict__ part,
                                               int* __restrict__ bsum) {
  __shared__ int sm[256];
  int t = threadIdx.x, b = blockIdx.x;
  int base = b * 1024 + t * 4;
  int v[4]; int s = 0;
#pragma unroll
  for (int q = 0; q < 4; ++q) { v[q] = (base + q < N_NODES) ? deg[base + q] : 0; s += v[q]; }
  sm[t] = s; __syncthreads();
  for (int off = 1; off < 256; off <<= 1) {
    int x = (t >= off) ? sm[t - off] : 0;
    __syncthreads();
    sm[t] += x;
    __syncthreads();
  }
  int run = sm[t] - s;
#pragma unroll
  for (int q = 0; q < 4; ++q) {
    if (base + q < N_NODES) part[base + q] = run;
    run += v[q];
  }
  if (t == 255) bsum[b] = sm[255];
}

// ---------- scan stage 2+3 merged: each block reduces bsum[0..b-1] itself ----------
__global__ __launch_bounds__(256) void k_scan3(const int* __restrict__ part,
                                               const int* __restrict__ bsum,
                                               int* __restrict__ rowptr,
                                               int* __restrict__ cursor,
                                               int* __restrict__ deg) {
  __shared__ int sm[128];
  int t = threadIdx.x, b = blockIdx.x;
  if (t < 128) sm[t] = (t < b) ? bsum[t] : 0;   // only blocks < b contribute (b <= 97 < 128)
  __syncthreads();
  for (int w = 64; w > 0; w >>= 1) {
    if (t < w) sm[t] += sm[t + w];
    __syncthreads();
  }
  int off = sm[0];
  int base = b * 1024 + t * 4;
#pragma unroll
  for (int q = 0; q < 4; ++q) {
    int i = base + q;
    if (i < N_NODES) {
      int r = part[i] + off;
      rowptr[i] = r;
      cursor[i] = r;
      deg[i] = __float_as_int(rsqrtf((float)(deg[i] + 1)));  // dinv in place
    }
  }
  if (b == 0 && t == 0) rowptr[N_NODES] = E_EDGES;
}

// ---------- fill CSR, XCD-range partitioned (8 blocks per chunk, range = blockIdx&7) ----------
__global__ __launch_bounds__(256) void k_fill(const int* __restrict__ ei,
                                              const int* __restrict__ dinv_bits,
                                              int* __restrict__ cursor,
                                              int2* __restrict__ srcw) {
  const int r    = blockIdx.x & 7;
  const int base = (blockIdx.x >> 3) * FCHUNK;
  const int lo   = r * RSIZE;
  const int hi   = lo + RSIZE;
#pragma unroll
  for (int i = 0; i < FCHUNK / 256; ++i) {
    int e = base + i * 256 + threadIdx.x;
    if (e < E_EDGES) {
      int d = ei[E_EDGES + e];
      if (d >= lo && d < hi) {
        int s = ei[e];
        int pos = atomicAdd(&cursor[d], 1);
        srcw[pos] = make_int2(s, dinv_bits[s]);
      }
    }
  }
}

// ---------- aggregate: quarter-wave per edge, 2 edges in flight per quarter ----------
__global__ __launch_bounds__(256) void k_agg(const int* __restrict__ rowptr,
                                             const int2* __restrict__ srcw,
                                             const float* __restrict__ dinv,
                                             const unsigned short* __restrict__ h,
                                             const float* __restrict__ bias,
                                             float* __restrict__ out) {
  const int t = threadIdx.x;
  const int n = blockIdx.x * 4 + (t >> 6);
  const int lane = t & 63;
  const int q  = lane >> 4;       // quarter 0..3
  const int li = lane & 15;       // lane-in-quarter; owns cols li*8..li*8+7
  const uint4* hq = (const uint4*)h;   // 16 uint4 per row
  float dn = dinv[n];
  int e1 = rowptr[n + 1];
  float accA[8], accB[8];
#pragma unroll
  for (int j = 0; j < 8; ++j) { accA[j] = 0.f; accB[j] = 0.f; }

  for (int e = rowptr[n] + q; e < e1; e += 8) {
    int2 sw = srcw[e];
    float wgt = __int_as_float(sw.y) * dn;
    uint4 v = hq[(long long)sw.x * 16 + li];
    int e2 = e + 4;
    if (e2 < e1) {
      int2 sw2 = srcw[e2];
      float wgt2 = __int_as_float(sw2.y) * dn;
      uint4 v2 = hq[(long long)sw2.x * 16 + li];
      accB[0] = fmaf(bf2f_lo(v2.x), wgt2, accB[0]);
      accB[1] = fmaf(bf2f_hi(v2.x), wgt2, accB[1]);
      accB[2] = fmaf(bf2f_lo(v2.y), wgt2, accB[2]);
      accB[3] = fmaf(bf2f_hi(v2.y), wgt2, accB[3]);
      accB[4] = fmaf(bf2f_lo(v2.z), wgt2, accB[4]);
      accB[5] = fmaf(bf2f_hi(v2.z), wgt2, accB[5]);
      accB[6] = fmaf(bf2f_lo(v2.w), wgt2, accB[6]);
      accB[7] = fmaf(bf2f_hi(v2.w), wgt2, accB[7]);
    }
    accA[0] = fmaf(bf2f_lo(v.x), wgt, accA[0]);
    accA[1] = fmaf(bf2f_hi(v.x), wgt, accA[1]);
    accA[2] = fmaf(bf2f_lo(v.y), wgt, accA[2]);
    accA[3] = fmaf(bf2f_hi(v.y), wgt, accA[3]);
    accA[4] = fmaf(bf2f_lo(v.z), wgt, accA[4]);
    accA[5] = fmaf(bf2f_hi(v.z), wgt, accA[5]);
    accA[6] = fmaf(bf2f_lo(v.w), wgt, accA[6]);
    accA[7] = fmaf(bf2f_hi(v.w), wgt, accA[7]);
  }
#pragma unroll
  for (int j = 0; j < 8; ++j) {
    float a = accA[j] + accB[j];
    a += __shfl_xor(a, 16);
    a += __shfl_xor(a, 32);
    accA[j] = a;
  }
  // lane finalizes cols c0 = li*8 + q*2, c0+1
  float a0 = accA[q * 2];
  float a1 = accA[q * 2 + 1];
  // self loop
  unsigned int hv = ((const unsigned int*)h)[(long long)n * 64 + li * 4 + q];
  float w2 = dn * dn;
  a0 = fmaf(bf2f_lo(hv), w2, a0);
  a1 = fmaf(bf2f_hi(hv), w2, a1);
  // bias + relu
  float2 bb = ((const float2*)bias)[li * 4 + q];
  float r0 = fmaxf(a0 + bb.x, 0.f);
  float r1 = fmaxf(a1 + bb.y, 0.f);
  // dropout: keep <=> top bit of threefry bits is 0
  unsigned int i0 = (unsigned int)n * 128u + (unsigned int)(li * 8 + q * 2);
  unsigned int b0 = threefry_bits(i0);
  unsigned int b1 = threefry_bits(i0 + 1u);
  float2 res;
  res.x = (b0 & 0x80000000u) ? 0.0f : r0 * 2.0f;
  res.y = (b1 & 0x80000000u) ? 0.0f : r1 * 2.0f;
  ((float2*)out)[(long long)n * 64 + li * 4 + q] = res;
}

extern "C" void kernel_launch(void* const* d_in, const int* in_sizes, int n_in,
                              void* d_out, int out_size, void* d_ws, size_t ws_size,
                              hipStream_t stream) {
  const float* x    = (const float*)d_in[0];
  const int*   ei   = (const int*)d_in[1];
  const float* w    = (const float*)d_in[2];
  const float* bias = (const float*)d_in[3];
  float* out = (float*)d_out;

  char* p = (char*)d_ws;
  unsigned short* h = (unsigned short*)p;   p += (size_t)N_NODES * D * 2;  // 25.6 MB
  int*  deg    = (int*)p;                   p += (size_t)N_NODES * 4;      // dinv after scan3
  int*  rowptr = (int*)p;                   p += (size_t)(N_NODES + 1) * 4;
  int*  cursor = (int*)p;                   p += (size_t)N_NODES * 4;
  int*  part   = (int*)p;                   p += (size_t)N_NODES * 4;
  int*  bsum   = (int*)p;                   p += 128 * 4;
  int2* srcw   = (int2*)p;                  p += (size_t)E_EDGES * 8;      // 12.8 MB

  hipMemsetAsync(deg, 0, (size_t)N_NODES * 4, stream);

  k_pre<<<GEMM_BLKS + DEG_BLKS, 256, 0, stream>>>(x, w, h, ei + E_EDGES, deg);
  k_scan1<<<NBLK_SCAN, 256, 0, stream>>>(deg, part, bsum);
  k_scan3<<<NBLK_SCAN, 256, 0, stream>>>(part, bsum, rowptr, cursor, deg);
  const int FILL_BLKS = ((E_EDGES + FCHUNK - 1) / FCHUNK) * NRANGE;  // 782*8
  k_fill<<<FILL_BLKS, 256, 0, stream>>>(ei, deg, cursor, srcw);
  const float* dinv = (const float*)deg;
  k_agg<<<N_NODES / 4, 256, 0, stream>>>(rowptr, srcw, dinv, h, bias, out);
}